// Round 5
// baseline (161.437 us; speedup 1.0000x reference)
//
#include <hip/hip_runtime.h>
#include <hip/hip_bf16.h>

typedef __attribute__((ext_vector_type(8))) short bf16x8;
typedef __attribute__((ext_vector_type(4))) float f32x4;

#define NB 4096
#define ND 512
#define MARGIN_F 0.2f

// order-preserving float -> uint encoding for atomicMax.
// enc(f) == 0 is impossible for finite f, so rowmax[a] == 0  <=>
// no wave ever found a different-label column in row a (has_neg == false).
__device__ __forceinline__ unsigned int enc_f32(float f) {
    unsigned int b = __float_as_uint(f);
    return (b & 0x80000000u) ? ~b : (b | 0x80000000u);
}

__device__ __forceinline__ float dec_f32(unsigned int e) {
    unsigned int b = (e & 0x80000000u) ? (e & 0x7fffffffu) : ~e;
    return __uint_as_float(b);
}

__device__ __forceinline__ void gld_lds16(const void* g, void* l) {
    __builtin_amdgcn_global_load_lds((__attribute__((address_space(1))) void*)g,
                                     (__attribute__((address_space(3))) void*)l,
                                     16, 0, 0);
}

// ---------------------------------------------------------------------------
// Prep: fp32 -> bf16 fragment-swizzled convert (both matrices), grid 2048.
// Blocks [0,16) zero the 4096-entry rowmax array; block 16 zeroes doneCnt.
// Swizzle: subtile = 16 rows x 32 cols; si = (row/16)*16 + (col/32);
// lane = (row%16) | (((col%32)/8)<<4); flat = si*512 + lane*8 + j.
// ---------------------------------------------------------------------------
__global__ __launch_bounds__(256) void k_prep(const float* __restrict__ zs,
                                              const float* __restrict__ zi,
                                              __hip_bfloat16* __restrict__ outb,
                                              unsigned int* __restrict__ rowmax,
                                              unsigned int* __restrict__ doneCnt) {
    const int bid = blockIdx.x;
    if (bid < 16) rowmax[bid * 256 + threadIdx.x] = 0u;
    if (bid == 16 && threadIdx.x == 0) *doneCnt = 0u;

    int gid = bid * 256 + threadIdx.x;   // [0, 2*4096*64)
    int mat = gid >> 18;                 // 0 = zs, 1 = zi
    int t   = gid & 0x3FFFF;
    int si  = t >> 6;
    int L   = t & 63;
    const float* src = mat ? zi : zs;
    int row = ((si >> 4) << 4) | (L & 15);
    int col = ((si & 15) << 5) | (((L >> 4) & 3) << 3);
    const float4* p = (const float4*)(src + (size_t)row * ND + col);
    float4 f0 = p[0];
    float4 f1 = p[1];
    union { __hip_bfloat16 h[8]; bf16x8 v; } u;
    u.h[0] = __float2bfloat16(f0.x);
    u.h[1] = __float2bfloat16(f0.y);
    u.h[2] = __float2bfloat16(f0.z);
    u.h[3] = __float2bfloat16(f0.w);
    u.h[4] = __float2bfloat16(f1.x);
    u.h[5] = __float2bfloat16(f1.y);
    u.h[6] = __float2bfloat16(f1.z);
    u.h[7] = __float2bfloat16(f1.w);
    bf16x8* dst = (bf16x8*)(outb + ((size_t)mat << 21) + ((size_t)si << 9) + (L << 3));
    *dst = u.v;
}

// ---------------------------------------------------------------------------
// 128x128 tile GEMM (S = Zs . Zi^T), BK=64, 4 waves, wave tile 64x64 as
// 4x4 of 16x16x32 bf16 MFMA. Epilogue: per-row different-label max ->
// atomicMax; diagonal blocks extract p_diag[a] = 1 - S[a][a] (atomicExch so
// the value is coherent at device scope). The last block to finish (device
// atomic done-counter) performs the final masked-mean reduction and writes
// out[0] -- this removes the separate finalize dispatch.
// ---------------------------------------------------------------------------
__global__ __launch_bounds__(256) void k_gemm_rowmax(const __hip_bfloat16* __restrict__ zsb,
                                                     const __hip_bfloat16* __restrict__ zib,
                                                     const int* __restrict__ labels,
                                                     unsigned int* __restrict__ rowmax,
                                                     float* __restrict__ p_diag,
                                                     unsigned int* __restrict__ doneCnt,
                                                     float* __restrict__ out) {
    __shared__ __align__(16) unsigned char sA[16384];   // 8 row-sub x 2 k-sub x 1KB
    __shared__ __align__(16) unsigned char sB[16384];
    __shared__ int labA[128];
    __shared__ int labB[128];

    const int tid = threadIdx.x;
    const int bx = blockIdx.x, by = blockIdx.y;

    if (tid < 128) labA[tid] = labels[by * 128 + tid];
    else           labB[tid - 128] = labels[bx * 128 + (tid - 128)];

    const char* gA = (const char*)zsb;
    const char* gB = (const char*)zib;
    const int rb0 = tid >> 7;              // 0/1
    const int rem = (tid & 127) << 4;      // covers kb*1024 + lane*16
    size_t aStat[4], bStat[4];
#pragma unroll
    for (int rd = 0; rd < 4; ++rd) {
        int rb = rd * 2 + rb0;             // local row-block 0..7
        aStat[rd] = ((size_t)(by * 8 + rb) << 14) + rem;   // *16384 bytes
        bStat[rd] = ((size_t)(bx * 8 + rb) << 14) + rem;
    }

    const int w = tid >> 6, lane = tid & 63;
    const int w_m = w >> 1, w_n = w & 1;
    const int fragOff = lane << 4;

    f32x4 acc[4][4];
#pragma unroll
    for (int i = 0; i < 4; ++i)
#pragma unroll
        for (int j = 0; j < 4; ++j)
            acc[i][j] = (f32x4){0.f, 0.f, 0.f, 0.f};

    for (int ks = 0; ks < 8; ++ks) {
        __syncthreads();
#pragma unroll
        for (int rd = 0; rd < 4; ++rd) {
            gld_lds16(gA + aStat[rd] + (size_t)ks * 2048, sA + rd * 4096 + (tid << 4));
            gld_lds16(gB + bStat[rd] + (size_t)ks * 2048, sB + rd * 4096 + (tid << 4));
        }
        __syncthreads();
#pragma unroll
        for (int kb = 0; kb < 2; ++kb) {
            bf16x8 af[4], bfr[4];
#pragma unroll
            for (int ms = 0; ms < 4; ++ms)
                af[ms] = *(const bf16x8*)(sA + (((w_m * 4 + ms) * 2 + kb) << 10) + fragOff);
#pragma unroll
            for (int ns = 0; ns < 4; ++ns)
                bfr[ns] = *(const bf16x8*)(sB + (((w_n * 4 + ns) * 2 + kb) << 10) + fragOff);
#pragma unroll
            for (int ms = 0; ms < 4; ++ms)
#pragma unroll
                for (int ns = 0; ns < 4; ++ns)
                    acc[ms][ns] = __builtin_amdgcn_mfma_f32_16x16x32_bf16(
                        af[ms], bfr[ns], acc[ms][ns], 0, 0, 0);
        }
    }

    // epilogue: C/D layout col = lane&15, row = (lane>>4)*4 + reg
    const int quad = lane >> 4;
    const int lcol = lane & 15;

    int lb[4];
#pragma unroll
    for (int ns = 0; ns < 4; ++ns)
        lb[ns] = labB[w_n * 64 + ns * 16 + lcol];

#pragma unroll
    for (int ms = 0; ms < 4; ++ms) {
        int la[4];
#pragma unroll
        for (int r = 0; r < 4; ++r)
            la[r] = labA[w_m * 64 + ms * 16 + quad * 4 + r];
        float mx[4] = {-3.0e38f, -3.0e38f, -3.0e38f, -3.0e38f};
#pragma unroll
        for (int ns = 0; ns < 4; ++ns) {
#pragma unroll
            for (int r = 0; r < 4; ++r) {
                float v = acc[ms][ns][r];
                if (la[r] != lb[ns] && v > mx[r]) mx[r] = v;
            }
        }
#pragma unroll
        for (int r = 0; r < 4; ++r) {
            float m = mx[r];
            m = fmaxf(m, __shfl_xor(m, 1));
            m = fmaxf(m, __shfl_xor(m, 2));
            m = fmaxf(m, __shfl_xor(m, 4));
            m = fmaxf(m, __shfl_xor(m, 8));
            // skip if this wave's 16-col slice had no different-label column
            if (lcol == 0 && m > -2.9e38f) {
                int rowg = by * 128 + w_m * 64 + ms * 16 + quad * 4 + r;
                atomicMax(&rowmax[rowg], enc_f32(m));
            }
        }
    }

    // diagonal blocks: extract p[a] = 1 - S[a][a] (device-scope atomic write
    // so the last block's atomic reads see it without fence subtleties).
    if (bx == by && w_m == w_n) {
        int r = lcol - quad * 4;
        if (r >= 0 && r < 4) {
#pragma unroll
            for (int ms = 0; ms < 4; ++ms) {
                int rowg = by * 128 + w_m * 64 + ms * 16 + lcol;
                atomicExch(&p_diag[rowg], 1.0f - acc[ms][ms][r]);
            }
        }
    }

    // ---- last-block-done finalize ----
    __threadfence();   // drain & order our epilogue atomics before done-count
    __shared__ unsigned int sIsLast;
    if (tid == 0) {
        unsigned int prev = atomicAdd(doneCnt, 1u);
        sIsLast = (prev == 32u * 32u - 1u) ? 1u : 0u;
    }
    __syncthreads();
    if (sIsLast) {
        __threadfence();
        float sum = 0.0f;
        int cnt = 0;
#pragma unroll
        for (int it = 0; it < 16; ++it) {
            int a = tid + it * 256;
            unsigned int e = atomicOr(&rowmax[a], 0u);          // coherent read
            if (e != 0u) {
                float n = 1.0f - dec_f32(e);
                float per = atomicAdd(&p_diag[a], 0.0f) - n + MARGIN_F;  // coherent read
                if (per > 0.0f) sum += per;
                cnt++;
            }
        }
#pragma unroll
        for (int off = 32; off > 0; off >>= 1) {
            sum += __shfl_xor(sum, off);
            cnt += __shfl_xor(cnt, off);
        }
        __shared__ float sSum[4];
        __shared__ int sCnt[4];
        if (lane == 0) { sSum[w] = sum; sCnt[w] = cnt; }
        __syncthreads();
        if (tid == 0) {
            float ts = sSum[0] + sSum[1] + sSum[2] + sSum[3];
            int tc = sCnt[0] + sCnt[1] + sCnt[2] + sCnt[3];
            out[0] = (tc > 0) ? ts / (float)tc : 0.0f;
        }
    }
}

extern "C" void kernel_launch(void* const* d_in, const int* in_sizes, int n_in,
                              void* d_out, int out_size, void* d_ws, size_t ws_size,
                              hipStream_t stream) {
    (void)in_sizes; (void)n_in; (void)out_size; (void)ws_size;
    const float* zs = (const float*)d_in[0];
    const float* zi = (const float*)d_in[1];
    const int* labels = (const int*)d_in[2];
    float* out = (float*)d_out;

    char* ws = (char*)d_ws;
    __hip_bfloat16* zb = (__hip_bfloat16*)ws;                       // 8 MB (zs then zi, swizzled)
    unsigned int* rowmax = (unsigned int*)(ws + (8u << 20));        // 16 KB
    float* p_diag = (float*)(ws + (8u << 20) + 16384);              // 16 KB
    unsigned int* doneCnt = (unsigned int*)(ws + (8u << 20) + 32768);

    k_prep<<<2048, 256, 0, stream>>>(zs, zi, zb, rowmax, doneCnt);
    dim3 g(32, 32);
    k_gemm_rowmax<<<g, 256, 0, stream>>>(zb, zb + (size_t)NB * ND, labels,
                                         rowmax, p_diag, doneCnt, out);
}

// Round 6
// 112.035 us; speedup vs baseline: 1.4409x; 1.4409x over previous
//
#include <hip/hip_runtime.h>
#include <hip/hip_bf16.h>

typedef __attribute__((ext_vector_type(8))) short bf16x8;
typedef __attribute__((ext_vector_type(4))) float f32x4;

#define NB 4096
#define ND 512
#define MARGIN_F 0.2f
#define SENTINEL -3.0e38f

__device__ __forceinline__ void gld_lds16(const void* g, void* l) {
    __builtin_amdgcn_global_load_lds((__attribute__((address_space(1))) void*)g,
                                     (__attribute__((address_space(3))) void*)l,
                                     16, 0, 0);
}

// ---------------------------------------------------------------------------
// Prep: fp32 -> bf16 fragment-swizzled convert (both matrices), grid 2048.
// Block 16 zeroes the finalize accumulators (doneCnt, sum, cnt).
// Swizzle: subtile = 16 rows x 32 cols; si = (row/16)*16 + (col/32);
// lane = (row%16) | (((col%32)/8)<<4); flat = si*512 + lane*8 + j.
// ---------------------------------------------------------------------------
__global__ __launch_bounds__(256) void k_prep(const float* __restrict__ zs,
                                              const float* __restrict__ zi,
                                              __hip_bfloat16* __restrict__ outb,
                                              unsigned int* __restrict__ ctrl) {
    const int bid = blockIdx.x;
    if (bid == 16 && threadIdx.x < 3) ctrl[threadIdx.x] = 0u;   // doneCnt, sumBits, cnt

    int gid = bid * 256 + threadIdx.x;   // [0, 2*4096*64)
    int mat = gid >> 18;                 // 0 = zs, 1 = zi
    int t   = gid & 0x3FFFF;
    int si  = t >> 6;
    int L   = t & 63;
    const float* src = mat ? zi : zs;
    int row = ((si >> 4) << 4) | (L & 15);
    int col = ((si & 15) << 5) | (((L >> 4) & 3) << 3);
    const float4* p = (const float4*)(src + (size_t)row * ND + col);
    float4 f0 = p[0];
    float4 f1 = p[1];
    union { __hip_bfloat16 h[8]; bf16x8 v; } u;
    u.h[0] = __float2bfloat16(f0.x);
    u.h[1] = __float2bfloat16(f0.y);
    u.h[2] = __float2bfloat16(f0.z);
    u.h[3] = __float2bfloat16(f0.w);
    u.h[4] = __float2bfloat16(f1.x);
    u.h[5] = __float2bfloat16(f1.y);
    u.h[6] = __float2bfloat16(f1.z);
    u.h[7] = __float2bfloat16(f1.w);
    bf16x8* dst = (bf16x8*)(outb + ((size_t)mat << 21) + ((size_t)si << 9) + (L << 3));
    *dst = u.v;
}

// ---------------------------------------------------------------------------
// 128x128 tile GEMM (S = Zs . Zi^T), BK=64, 4 waves, wave tile 64x64 as
// 4x4 of 16x16x32 bf16 MFMA. Epilogue: per-row different-label max over this
// wave's 64 columns -> PLAIN STORE to partial[bx*2+w_n][row] (no atomics —
// device atomicMax to 4096 hot words was the R3/R4-invariant ~30us cost).
// Sentinel -3e38 survives when a slice had no different-label column.
// Diagonal blocks also store p_diag[a] = 1 - S[a][a].
// ---------------------------------------------------------------------------
__global__ __launch_bounds__(256) void k_gemm_rowmax(const __hip_bfloat16* __restrict__ zsb,
                                                     const __hip_bfloat16* __restrict__ zib,
                                                     const int* __restrict__ labels,
                                                     float* __restrict__ partial,
                                                     float* __restrict__ p_diag) {
    __shared__ __align__(16) unsigned char sA[16384];   // 8 row-sub x 2 k-sub x 1KB
    __shared__ __align__(16) unsigned char sB[16384];
    __shared__ int labA[128];
    __shared__ int labB[128];

    const int tid = threadIdx.x;
    const int bx = blockIdx.x, by = blockIdx.y;

    if (tid < 128) labA[tid] = labels[by * 128 + tid];
    else           labB[tid - 128] = labels[bx * 128 + (tid - 128)];

    const char* gA = (const char*)zsb;
    const char* gB = (const char*)zib;
    const int rb0 = tid >> 7;              // 0/1
    const int rem = (tid & 127) << 4;      // covers kb*1024 + lane*16
    size_t aStat[4], bStat[4];
#pragma unroll
    for (int rd = 0; rd < 4; ++rd) {
        int rb = rd * 2 + rb0;             // local row-block 0..7
        aStat[rd] = ((size_t)(by * 8 + rb) << 14) + rem;   // *16384 bytes
        bStat[rd] = ((size_t)(bx * 8 + rb) << 14) + rem;
    }

    const int w = tid >> 6, lane = tid & 63;
    const int w_m = w >> 1, w_n = w & 1;
    const int fragOff = lane << 4;

    f32x4 acc[4][4];
#pragma unroll
    for (int i = 0; i < 4; ++i)
#pragma unroll
        for (int j = 0; j < 4; ++j)
            acc[i][j] = (f32x4){0.f, 0.f, 0.f, 0.f};

    for (int ks = 0; ks < 8; ++ks) {
        __syncthreads();
#pragma unroll
        for (int rd = 0; rd < 4; ++rd) {
            gld_lds16(gA + aStat[rd] + (size_t)ks * 2048, sA + rd * 4096 + (tid << 4));
            gld_lds16(gB + bStat[rd] + (size_t)ks * 2048, sB + rd * 4096 + (tid << 4));
        }
        __syncthreads();
#pragma unroll
        for (int kb = 0; kb < 2; ++kb) {
            bf16x8 af[4], bfr[4];
#pragma unroll
            for (int ms = 0; ms < 4; ++ms)
                af[ms] = *(const bf16x8*)(sA + (((w_m * 4 + ms) * 2 + kb) << 10) + fragOff);
#pragma unroll
            for (int ns = 0; ns < 4; ++ns)
                bfr[ns] = *(const bf16x8*)(sB + (((w_n * 4 + ns) * 2 + kb) << 10) + fragOff);
#pragma unroll
            for (int ms = 0; ms < 4; ++ms)
#pragma unroll
                for (int ns = 0; ns < 4; ++ns)
                    acc[ms][ns] = __builtin_amdgcn_mfma_f32_16x16x32_bf16(
                        af[ms], bfr[ns], acc[ms][ns], 0, 0, 0);
        }
    }

    // epilogue: C/D layout col = lane&15, row = (lane>>4)*4 + reg
    const int quad = lane >> 4;
    const int lcol = lane & 15;

    int lb[4];
#pragma unroll
    for (int ns = 0; ns < 4; ++ns)
        lb[ns] = labB[w_n * 64 + ns * 16 + lcol];

    float* slot = partial + ((size_t)(bx * 2 + w_n) << 12) + by * 128 + w_m * 64;

#pragma unroll
    for (int ms = 0; ms < 4; ++ms) {
        int la[4];
#pragma unroll
        for (int r = 0; r < 4; ++r)
            la[r] = labA[w_m * 64 + ms * 16 + quad * 4 + r];
        float mx[4] = {SENTINEL, SENTINEL, SENTINEL, SENTINEL};
#pragma unroll
        for (int ns = 0; ns < 4; ++ns) {
#pragma unroll
            for (int r = 0; r < 4; ++r) {
                float v = acc[ms][ns][r];
                if (la[r] != lb[ns] && v > mx[r]) mx[r] = v;
            }
        }
#pragma unroll
        for (int r = 0; r < 4; ++r) {
            float m = mx[r];
            m = fmaxf(m, __shfl_xor(m, 1));
            m = fmaxf(m, __shfl_xor(m, 2));
            m = fmaxf(m, __shfl_xor(m, 4));
            m = fmaxf(m, __shfl_xor(m, 8));
            if (lcol == 0)
                slot[ms * 16 + quad * 4 + r] = m;
        }
    }

    // diagonal blocks: extract p[a] = 1 - S[a][a] (plain stores)
    if (bx == by && w_m == w_n) {
        int r = lcol - quad * 4;
        if (r >= 0 && r < 4) {
#pragma unroll
            for (int ms = 0; ms < 4; ++ms) {
                int rowg = by * 128 + w_m * 64 + ms * 16 + lcol;
                p_diag[rowg] = 1.0f - acc[ms][ms][r];
            }
        }
    }
}

// ---------------------------------------------------------------------------
// Finalize: 16 blocks x 256 threads, one row per thread (256 rows/block).
// rowbest = max over 64 partial slots; has_neg = rowbest > sentinel;
// per = relu(p - (1 - rowbest) + margin); block sums -> device atomics;
// last of 16 blocks (16 fences only) computes the mean and writes out[0].
// ---------------------------------------------------------------------------
__global__ __launch_bounds__(256) void k_finalize(const float* __restrict__ partial,
                                                  const float* __restrict__ p_diag,
                                                  unsigned int* __restrict__ ctrl,
                                                  float* __restrict__ out) {
    const int tid = threadIdx.x;
    const int a = blockIdx.x * 256 + tid;

    float best = SENTINEL;
#pragma unroll 8
    for (int s = 0; s < 64; ++s) {
        float v = partial[((size_t)s << 12) + a];
        best = fmaxf(best, v);
    }

    float sum = 0.0f;
    int cnt = 0;
    if (best > -2.9e38f) {
        float per = p_diag[a] - (1.0f - best) + MARGIN_F;
        if (per > 0.0f) sum = per;
        cnt = 1;
    }

#pragma unroll
    for (int off = 32; off > 0; off >>= 1) {
        sum += __shfl_xor(sum, off);
        cnt += __shfl_xor(cnt, off);
    }
    __shared__ float sSum[4];
    __shared__ int sCnt[4];
    int w = tid >> 6, lane = tid & 63;
    if (lane == 0) { sSum[w] = sum; sCnt[w] = cnt; }
    __syncthreads();

    __shared__ unsigned int sIsLast;
    if (tid == 0) {
        float ts = sSum[0] + sSum[1] + sSum[2] + sSum[3];
        unsigned int tc = (unsigned int)(sCnt[0] + sCnt[1] + sCnt[2] + sCnt[3]);
        atomicAdd((float*)&ctrl[1], ts);
        atomicAdd(&ctrl[2], tc);
        __threadfence();
        unsigned int prev = atomicAdd(&ctrl[0], 1u);
        sIsLast = (prev == 15u) ? 1u : 0u;
    }
    __syncthreads();
    if (sIsLast && tid == 0) {
        __threadfence();
        float ts = atomicAdd((float*)&ctrl[1], 0.0f);
        unsigned int tc = atomicAdd(&ctrl[2], 0u);
        out[0] = (tc > 0u) ? ts / (float)tc : 0.0f;
    }
}

extern "C" void kernel_launch(void* const* d_in, const int* in_sizes, int n_in,
                              void* d_out, int out_size, void* d_ws, size_t ws_size,
                              hipStream_t stream) {
    (void)in_sizes; (void)n_in; (void)out_size; (void)ws_size;
    const float* zs = (const float*)d_in[0];
    const float* zi = (const float*)d_in[1];
    const int* labels = (const int*)d_in[2];
    float* out = (float*)d_out;

    char* ws = (char*)d_ws;
    __hip_bfloat16* zb = (__hip_bfloat16*)ws;                       // 8 MB (zs then zi, swizzled)
    float* partial = (float*)(ws + (8u << 20));                     // 1 MB: [64][4096]
    float* p_diag = (float*)(ws + (9u << 20));                      // 16 KB
    unsigned int* ctrl = (unsigned int*)(ws + (9u << 20) + 16384);  // doneCnt, sumBits, cnt

    k_prep<<<2048, 256, 0, stream>>>(zs, zi, zb, ctrl);
    dim3 g(32, 32);
    k_gemm_rowmax<<<g, 256, 0, stream>>>(zb, zb + (size_t)NB * ND, labels, partial, p_diag);
    k_finalize<<<16, 256, 0, stream>>>(partial, p_diag, ctrl, out);
}